// Round 1
// baseline (179.659 us; speedup 1.0000x reference)
//
#include <hip/hip_runtime.h>

#define N_FEAT 128
#define HID 256
#define OUT_CH 128

#define NB 256        // CSR-build blocks (per-block histograms)
#define MAXN 10240    // LDS histogram capacity (N=10000)

typedef unsigned short u16;
typedef _Float16 f16x8 __attribute__((ext_vector_type(8)));
typedef float f32x4 __attribute__((ext_vector_type(4)));

// ---------------- f16 pack/unpack helpers ----------------
// Tables switched bf16 -> f16 (same bytes, 4x less rounding error) to buy
// margin for the new f16 MFMA GEMMs.
__device__ __forceinline__ unsigned pack_f16x2(float lo, float hi) {
    union { _Float16 h[2]; unsigned u; } c;
    c.h[0] = (_Float16)lo;
    c.h[1] = (_Float16)hi;
    return c.u;
}
__device__ __forceinline__ float2 unpack_f16x2(unsigned u) {
    union { unsigned u; _Float16 h[2]; } c;
    c.u = u;
    return make_float2((float)c.h[0], (float)c.h[1]);
}
__device__ __forceinline__ u16 f16u(float f) {
    union { _Float16 h; u16 u; } c;
    c.h = (_Float16)f;
    return c.u;
}

// ---------------- CSR build: LDS-histogram counting sort ----------------

__global__ __launch_bounds__(256)
void hist_kernel(const int* __restrict__ dst, u16* __restrict__ bh,
                 int E, int N, int chunk) {
    __shared__ int hist[MAXN];
    for (int i = threadIdx.x; i < N; i += 256) hist[i] = 0;
    __syncthreads();
    int base = blockIdx.x * chunk;
    int lim = min(chunk, E - base);
    for (int i = threadIdx.x; i < lim; i += 256) {
        int d = dst[base + i];
        if (d >= 0 && d < N) atomicAdd(&hist[d], 1);
    }
    __syncthreads();
    u16* out = bh + (size_t)blockIdx.x * N;
    for (int i = threadIdx.x; i < N; i += 256) out[i] = (u16)hist[i];
}

// Fused column scan: bh[b][j] <- per-column exclusive block prefix (replaces
// the old ps/chunkbase pair: one fewer kernel, -1.3MB ps traffic, -10MB bh
// re-traffic). Also emits counts + dinv.
__global__ __launch_bounds__(256)
void colscan_kernel(u16* __restrict__ bh,
                    int* __restrict__ counts, float* __restrict__ dinv, int N) {
    int j = blockIdx.x * 256 + threadIdx.x;
    if (j >= N) return;
    int run = 0;
    #pragma unroll 8
    for (int b = 0; b < NB; b++) {
        size_t idx = (size_t)b * N + j;
        int t = bh[idx];
        bh[idx] = (u16)run;
        run += t;
    }
    counts[j] = run;
    dinv[j] = rsqrtf((float)(run + 1));
}

// Single-block hybrid scan: row_start = exclusive-scan(counts).
#define SCAN_T 1024
#define SCAN_MAX_PER 16
__global__ __launch_bounds__(SCAN_T)
void scan_kernel(const int* __restrict__ counts,
                 int* __restrict__ row_start, int n) {
    int tid = threadIdx.x;
    int per = (n + SCAN_T - 1) / SCAN_T;
    int base = tid * per;
    int local[SCAN_MAX_PER];
    int sum = 0;
    for (int j = 0; j < per; j++) {
        int i = base + j;
        int c = (i < n) ? counts[i] : 0;
        local[j] = sum;
        sum += c;
    }
    int lane = tid & 63;
    int wave = tid >> 6;
    int incl = sum;
    #pragma unroll
    for (int off = 1; off < 64; off <<= 1) {
        int t = __shfl_up(incl, off, 64);
        if (lane >= off) incl += t;
    }
    __shared__ int wsum[16];
    __shared__ int woff[16];
    if (lane == 63) wsum[wave] = incl;
    __syncthreads();
    if (wave == 0) {
        int w = (lane < 16) ? wsum[lane] : 0;
        int v = w;
        #pragma unroll
        for (int off = 1; off < 16; off <<= 1) {
            int t = __shfl_up(v, off, 64);
            if (lane >= off) v += t;
        }
        if (lane < 16) woff[lane] = v - w;
    }
    __syncthreads();
    int thread_excl = woff[wave] + (incl - sum);
    for (int j = 0; j < per; j++) {
        int i = base + j;
        if (i < n) row_start[i] = thread_excl + local[j];
    }
    if (tid == SCAN_T - 1) row_start[n] = thread_excl + sum;
}

// Scatter via LDS cursors (no global atomics).
__global__ __launch_bounds__(256)
void scat_kernel(const int* __restrict__ src, const int* __restrict__ dst,
                 const u16* __restrict__ bh,
                 const int* __restrict__ row_start,
                 int* __restrict__ csr_src, int E, int N, int chunk) {
    __shared__ int cur[MAXN];
    const u16* basep = bh + (size_t)blockIdx.x * N;
    for (int i = threadIdx.x; i < N; i += 256)
        cur[i] = row_start[i] + (int)basep[i];
    __syncthreads();
    int base = blockIdx.x * chunk;
    int lim = min(chunk, E - base);
    for (int i = threadIdx.x; i < lim; i += 256) {
        int e = base + i;
        int d = dst[e];
        if (d < 0 || d >= N) continue;
        int pos = atomicAdd(&cur[d], 1);
        if ((unsigned)pos < (unsigned)E) csr_src[pos] = src[e];
    }
}

// ---------------- prescale (f16 table) + W1/W2 -> f16 transposed ----------------
// W conversion folded into this grid's tail: no extra launch.
__global__ void prescale_kernel(const float* __restrict__ x,
                                const float* __restrict__ dinv,
                                unsigned* __restrict__ xs_b,
                                const float* __restrict__ W1,
                                const float* __restrict__ W2,
                                u16* __restrict__ W1t, u16* __restrict__ W2t,
                                int total4) {
    int i = blockIdx.x * blockDim.x + threadIdx.x;
    if (i < total4) {
        int row = i >> 5;                // 32 float4 per 128-f row
        float d = dinv[row];
        float4 v = ((const float4*)x)[i];
        uint2 p;
        p.x = pack_f16x2(v.x * d, v.y * d);
        p.y = pack_f16x2(v.z * d, v.w * d);
        ((uint2*)xs_b)[i] = p;
    } else {
        int j = i - total4;
        if (j < N_FEAT * HID) {          // W1t[n][k] = W1[k][n], f16 [256][128]
            int n = j >> 7, k = j & 127;
            W1t[j] = f16u(W1[(size_t)k * HID + n]);
        } else {
            j -= N_FEAT * HID;           // W2t[n][k] = W2[k][n], f16 [128][256]
            if (j < HID * OUT_CH) {
                int n = j >> 8, k = j & 255;
                W2t[j] = f16u(W2[(size_t)k * OUT_CH + n]);
            }
        }
    }
}

// ---------------- Aggregation (f16 table, fp32 accumulate) ----------------
// Structure proven over rounds 7-14: 4 waves/block, one node/wave, 64 lanes x
// f16x2, software-pipelined batch-8 edge loop. Only change: f16 unpack and
// optional f16 output (feeds the MFMA GEMM directly).
template <bool EPILOGUE, bool F16OUT>
__global__ __launch_bounds__(256)
void agg_kernel(const unsigned* __restrict__ featb,
                const float* __restrict__ dinv,
                const int* __restrict__ row_start,
                const int* __restrict__ csr_src,
                const float* __restrict__ bias,
                void* __restrict__ out, int N) {
    int wave = threadIdx.x >> 6;
    int n = blockIdx.x * 4 + wave;
    if (n >= N) return;
    int f = threadIdx.x & 63;
    float dn = dinv[n];
    float2 v = unpack_f16x2(featb[(size_t)n * 64 + f]);
    float accx = v.x;
    float accy = v.y;
    int e0 = row_start[n];
    int e1 = row_start[n + 1];
    int e = e0;
    if (e + 8 <= e1) {
        int s_cur[8];
        #pragma unroll
        for (int j = 0; j < 8; j++) s_cur[j] = csr_src[e + j];
        e += 8;
        for (; e + 8 <= e1; e += 8) {
            unsigned w[8];
            #pragma unroll
            for (int j = 0; j < 8; j++) w[j] = featb[(size_t)s_cur[j] * 64 + f];
            int s_nxt[8];
            #pragma unroll
            for (int j = 0; j < 8; j++) s_nxt[j] = csr_src[e + j];
            #pragma unroll
            for (int j = 0; j < 8; j++) {
                float2 u = unpack_f16x2(w[j]);
                accx += u.x;
                accy += u.y;
            }
            #pragma unroll
            for (int j = 0; j < 8; j++) s_cur[j] = s_nxt[j];
        }
        unsigned w[8];
        #pragma unroll
        for (int j = 0; j < 8; j++) w[j] = featb[(size_t)s_cur[j] * 64 + f];
        #pragma unroll
        for (int j = 0; j < 8; j++) {
            float2 u = unpack_f16x2(w[j]);
            accx += u.x;
            accy += u.y;
        }
    }
    for (; e + 4 <= e1; e += 4) {
        int s0 = csr_src[e], s1 = csr_src[e + 1];
        int s2 = csr_src[e + 2], s3 = csr_src[e + 3];
        unsigned w0 = featb[(size_t)s0 * 64 + f];
        unsigned w1 = featb[(size_t)s1 * 64 + f];
        unsigned w2 = featb[(size_t)s2 * 64 + f];
        unsigned w3 = featb[(size_t)s3 * 64 + f];
        float2 u0 = unpack_f16x2(w0), u1 = unpack_f16x2(w1);
        float2 u2 = unpack_f16x2(w2), u3 = unpack_f16x2(w3);
        accx += u0.x + u1.x + u2.x + u3.x;
        accy += u0.y + u1.y + u2.y + u3.y;
    }
    for (; e < e1; ++e) {
        float2 u = unpack_f16x2(featb[(size_t)csr_src[e] * 64 + f]);
        accx += u.x;
        accy += u.y;
    }
    accx *= dn;
    accy *= dn;
    if (EPILOGUE) {
        float2 b = ((const float2*)bias)[f];
        accx = fmaxf(accx + b.x, 0.0f);
        accy = fmaxf(accy + b.y, 0.0f);
    }
    if (F16OUT) {
        ((unsigned*)out)[(size_t)n * 64 + f] = pack_f16x2(accx, accy);
    } else {
        float2 r;
        r.x = accx;
        r.y = accy;
        ((float2*)out)[(size_t)n * 64 + f] = r;
    }
}

// ---------------- f16 MFMA GEMM: C[M,N] = A[M,K] @ Bt[N,K]^T ----------------
// 64x64 tile, 4 waves; wave w owns rows [w*16,w*16+16) x 64 cols = 4 accum
// frags of mfma_f32_16x16x32_f16 (fp32 accumulate). LDS tiles XOR-swizzled
// (chunk ^ (row&7)) so ds_read_b128 fragment loads are conflict-free (G4/T2).
// A rows are read unguarded up to the 64-row-padded M (allocations padded);
// garbage rows only feed garbage output rows, which the store guard drops.
template <bool BIAS_RELU, bool RSCALE>
__global__ __launch_bounds__(256)
void gemm16_kernel(const u16* __restrict__ A,    // [Mpad][K] f16 row-major
                   const u16* __restrict__ Bt,   // [N][K]   f16 row-major
                   const float* __restrict__ bias,
                   const float* __restrict__ rscale,
                   u16* __restrict__ C,          // [M][N]   f16 row-major
                   int M, int N, int K) {
    __shared__ __align__(16) u16 As[64][64];
    __shared__ __align__(16) u16 Bs[64][64];
    int tid = threadIdx.x;
    int w = tid >> 6;
    int l = tid & 63;
    int m0 = blockIdx.y * 64;
    int n0 = blockIdx.x * 64;

    f32x4 acc[4];
    const f32x4 zero = {0.f, 0.f, 0.f, 0.f};
    #pragma unroll
    for (int n = 0; n < 4; n++) acc[n] = zero;

    int rowA = w * 16 + (l & 15);   // A-frag row (M dim)
    int cbase = l >> 4;             // k-chunk sub-index 0..3

    for (int k0 = 0; k0 < K; k0 += 64) {
        #pragma unroll
        for (int t = 0; t < 2; t++) {
            int q = tid + t * 256;        // 512 16B-chunks per 64x64 f16 tile
            int r = q >> 3;
            int c = q & 7;
            f16x8 av = *(const f16x8*)(A + (size_t)(m0 + r) * K + k0 + c * 8);
            *(f16x8*)&As[r][(c ^ (r & 7)) * 8] = av;
            f16x8 bv = *(const f16x8*)(Bt + (size_t)(n0 + r) * K + k0 + c * 8);
            *(f16x8*)&Bs[r][(c ^ (r & 7)) * 8] = bv;
        }
        __syncthreads();
        #pragma unroll
        for (int kc = 0; kc < 2; kc++) {
            int ch = kc * 4 + cbase;      // lane's 8-elem k-chunk within 64
            f16x8 af = *(const f16x8*)&As[rowA][(ch ^ (rowA & 7)) * 8];
            #pragma unroll
            for (int n = 0; n < 4; n++) {
                int rb = n * 16 + (l & 15);
                f16x8 bf = *(const f16x8*)&Bs[rb][(ch ^ (rb & 7)) * 8];
                acc[n] = __builtin_amdgcn_mfma_f32_16x16x32_f16(af, bf, acc[n], 0, 0, 0);
            }
        }
        __syncthreads();
    }
    // epilogue: D lane mapping col = lane&15, row = (lane>>4)*4 + reg (m89)
    int r0 = (l >> 4) * 2 * 2;  // (l>>4)*4
    int col_l = l & 15;
    #pragma unroll
    for (int r = 0; r < 4; r++) {
        int m = m0 + w * 16 + r0 + r;
        if (m >= M) continue;
        float rs = RSCALE ? rscale[m] : 1.0f;
        #pragma unroll
        for (int n = 0; n < 4; n++) {
            int col = n0 + n * 16 + col_l;
            float v = acc[n][r];
            if (RSCALE) v *= rs;
            if (BIAS_RELU) v = fmaxf(v + bias[col], 0.0f);
            C[(size_t)m * N + col] = f16u(v);
        }
    }
}

// ---------------- launch ----------------

static inline size_t align512(size_t x) { return (x + 511) & ~(size_t)511; }

extern "C" void kernel_launch(void* const* d_in, const int* in_sizes, int n_in,
                              void* d_out, int out_size, void* d_ws, size_t ws_size,
                              hipStream_t stream) {
    const float* x = (const float*)d_in[0];
    const int* ei = (const int*)d_in[1];
    const float* W1 = (const float*)d_in[2];
    const float* b1 = (const float*)d_in[3];
    const float* W2 = (const float*)d_in[4];
    const float* b2 = (const float*)d_in[5];
    float* out = (float*)d_out;

    const int N = in_sizes[0] / N_FEAT;      // 10000
    const int E = in_sizes[1] / 2;           // 640000
    const int* src = ei;
    const int* dst = ei + E;

    const int Mpad = ((N + 63) / 64) * 64;   // 10048 (MFMA staging pad)

    // workspace carve-up (~21 MB)
    char* ws = (char*)d_ws;
    size_t off = 0;
    float* dinv = (float*)(ws + off);    off += align512((size_t)N * 4);
    int* counts = (int*)(ws + off);      off += align512((size_t)N * 4);
    int* row_start = (int*)(ws + off);   off += align512((size_t)(N + 1) * 4);
    int* csr_src = (int*)(ws + off);     off += align512((size_t)E * 4);
    unsigned* xs_b = (unsigned*)(ws + off);  off += align512((size_t)N * 64 * 4);
    u16* agg1h = (u16*)(ws + off);       off += align512((size_t)Mpad * N_FEAT * 2);
    u16* h16 = (u16*)(ws + off);         off += align512((size_t)Mpad * HID * 2);
    u16* t16 = (u16*)(ws + off);         off += align512((size_t)N * OUT_CH * 2);
    u16* W1t = (u16*)(ws + off);         off += align512((size_t)HID * N_FEAT * 2);
    u16* W2t = (u16*)(ws + off);         off += align512((size_t)OUT_CH * HID * 2);
    u16* bh = (u16*)(ws + off);          off += align512((size_t)NB * N * 2);
    (void)ws_size;
    const int chunk = (E + NB - 1) / NB;
    const int NJ = (N + 255) / 256;

    // 1. CSR build (chunkbase fused into colscan; ps eliminated)
    hist_kernel<<<NB, 256, 0, stream>>>(dst, bh, E, N, chunk);
    colscan_kernel<<<NJ, 256, 0, stream>>>(bh, counts, dinv, N);
    scan_kernel<<<1, SCAN_T, 0, stream>>>(counts, row_start, N);
    scat_kernel<<<NB, 256, 0, stream>>>(src, dst, bh, row_start, csr_src, E, N, chunk);

    // 2. xs_b = f16(dinv[row] * x); tail converts W1/W2 -> f16 transposed
    {
        int total4 = N * N_FEAT / 4;
        int total = total4 + N_FEAT * HID + HID * OUT_CH;
        prescale_kernel<<<(total + 255) / 256, 256, 0, stream>>>(
            x, dinv, xs_b, W1, W2, W1t, W2t, total4);
    }

    // 3. agg1h = f16(A_norm @ x)
    agg_kernel<false, true><<<(N + 3) / 4, 256, 0, stream>>>(
        xs_b, dinv, row_start, csr_src, nullptr, agg1h, N);

    // 4. h16 = f16(relu(agg1h @ W1 + b1))   [MFMA]
    {
        dim3 grid(HID / 64, Mpad / 64);
        gemm16_kernel<true, false><<<grid, 256, 0, stream>>>(
            agg1h, W1t, b1, nullptr, h16, N, HID, N_FEAT);
    }

    // 5. t16 = f16(dinv[m] * (h16 @ W2))    [MFMA]
    {
        dim3 grid(OUT_CH / 64, Mpad / 64);
        gemm16_kernel<false, true><<<grid, 256, 0, stream>>>(
            h16, W2t, nullptr, dinv, t16, N, OUT_CH, HID);
    }

    // 6. out = relu(A_norm-aggregate of t16 + b2)
    agg_kernel<true, false><<<(N + 3) / 4, 256, 0, stream>>>(
        (const unsigned*)t16, dinv, row_start, csr_src, b2, out, N);
}